// Round 1
// baseline (763.740 us; speedup 1.0000x reference)
//
#include <hip/hip_runtime.h>

// ROI mean-pool for YOLOv8 feature maps.
// fmap:  [B=64, C=256, H=80, W=80] fp32
// boxes: [B=64, N=100, 4] xyxy in [0,640]
// out:   [B, N, C] fp32; empty (int-truncated) boxes -> 0.
//
// Strategy: one block per (b,c) plane. Plane -> LDS (float4, coalesced,
// each HBM byte read exactly once = 419 MB total). Column-wise inclusive
// cumsum in LDS, then per-box x-range sums of row differences with a
// wave-level shuffle reduction. HBM-roofline ~68 us.

constexpr int Bc = 64, Cc = 256, Hc = 80, Wc = 80, Nc = 100;
constexpr int HWc = Hc * Wc;

__global__ __launch_bounds__(256) void roi_mean_pool_kernel(
    const float* __restrict__ fmap,
    const float* __restrict__ boxes,
    float* __restrict__ out)
{
    __shared__ float s[HWc];               // 25.6 KB -> up to 6 blocks/CU

    const int tid = threadIdx.x;
    const int bc  = blockIdx.x;            // = b*Cc + c
    const int b   = bc >> 8;               // Cc == 256
    const int c   = bc & 255;

    // ---- Phase 1: stream this channel plane into LDS (float4) ----
    {
        const float4* __restrict__ src = (const float4*)(fmap + (size_t)bc * HWc);
        float4* dst = (float4*)s;
        #pragma unroll
        for (int i = tid; i < HWc / 4; i += 256) dst[i] = src[i];
    }
    __syncthreads();

    // ---- Phase 2: inclusive cumsum down each column (axis y) ----
    // lane x -> column x; consecutive addresses across lanes => conflict-free.
    if (tid < Wc) {
        float run = s[tid];
        #pragma unroll 4
        for (int y = 1; y < Hc; ++y) {
            run += s[y * Wc + tid];
            s[y * Wc + tid] = run;
        }
    }
    __syncthreads();

    // ---- Phase 3: one wave per box ----
    const int wave = tid >> 6;
    const int lane = tid & 63;
    const float* __restrict__ bb = boxes + (size_t)b * Nc * 4;

    for (int n = wave; n < Nc; n += 4) {
        // Box coords are wave-uniform (same address for all lanes).
        const float bx1 = bb[n * 4 + 0];
        const float by1 = bb[n * 4 + 1];
        const float bx2 = bb[n * 4 + 2];
        const float by2 = bb[n * 4 + 3];

        // Mirror reference: (coord / 640) * 80, truncate to int, clip [0,80].
        int x1 = (int)(bx1 / 640.0f * 80.0f);
        int y1 = (int)(by1 / 640.0f * 80.0f);
        int x2 = (int)(bx2 / 640.0f * 80.0f);
        int y2 = (int)(by2 / 640.0f * 80.0f);
        x1 = min(max(x1, 0), Wc);  x2 = min(max(x2, 0), Wc);
        y1 = min(max(y1, 0), Hc);  y2 = min(max(y2, 0), Hc);

        const int dx = x2 - x1;
        const int dy = y2 - y1;

        float v = 0.0f;
        if (dx > 0 && dy > 0) {            // wave-uniform branch
            float sum = 0.0f;
            for (int x = x1 + lane; x < x2; x += 64) {
                const float top = s[(y2 - 1) * Wc + x];
                const float bot = (y1 > 0) ? s[(y1 - 1) * Wc + x] : 0.0f;
                sum += top - bot;
            }
            #pragma unroll
            for (int off = 32; off > 0; off >>= 1)
                sum += __shfl_xor(sum, off, 64);
            v = sum / (float)(dy * dx);
        }
        if (lane == 0)
            out[((size_t)b * Nc + n) * Cc + c] = v;
    }
}

extern "C" void kernel_launch(void* const* d_in, const int* in_sizes, int n_in,
                              void* d_out, int out_size, void* d_ws, size_t ws_size,
                              hipStream_t stream) {
    const float* fmap  = (const float*)d_in[0];
    const float* boxes = (const float*)d_in[1];
    float* out = (float*)d_out;

    dim3 grid(Bc * Cc);   // 16384 blocks
    dim3 block(256);
    roi_mean_pool_kernel<<<grid, block, 0, stream>>>(fmap, boxes, out);
}

// Round 2
// 541.937 us; speedup vs baseline: 1.4093x; 1.4093x over previous
//
#include <hip/hip_runtime.h>

// ROI mean-pool for YOLOv8 feature maps.
// fmap:  [B=64, C=256, H=80, W=80] fp32
// boxes: [B=64, N=100, 4] xyxy in [0,640]
// out:   [B, N, C] fp32; empty (int-truncated) boxes -> 0.
//
// R2 structure: one block per (b,c) plane.
//  P1: plane -> LDS (float4 global, each HBM byte read exactly once).
//  P2: full 2D integral image in LDS (81x81 with zero border).
//      col pass: thread=column, addresses consecutive across lanes (free).
//      row pass: thread=row, stride 81 == 17 mod 32 (odd) -> conflict-free.
//  P3: ONE THREAD PER BOX: 4 LDS lookups + inclusion-exclusion. No x-loop,
//      no shuffle reduction, no lane-redundant coordinate math.

constexpr int Bc = 64, Cc = 256, Hc = 80, Wc = 80, Nc = 100;
constexpr int PW = 81;                    // padded/bordered width (odd -> no bank conflicts)
constexpr int PSZ = PW * PW;              // 6561 floats = 26.2 KB

__global__ __launch_bounds__(256) void roi_mean_pool_kernel(
    const float* __restrict__ fmap,
    const float* __restrict__ boxes,
    float* __restrict__ out)
{
    __shared__ float s[PSZ];              // P[y][x] at s[y*81+x]; row0/col0 = 0

    const int tid = threadIdx.x;
    const int bc  = blockIdx.x;           // = b*Cc + c
    const int b   = bc >> 8;              // Cc == 256
    const int c   = bc & 255;

    // ---- Phase 1: stream plane into bordered LDS (float4 global loads) ----
    {
        const float4* __restrict__ src = (const float4*)(fmap + (size_t)bc * (Hc * Wc));
        #pragma unroll
        for (int i = tid; i < (Hc * Wc) / 4; i += 256) {   // 1600 float4s, ~7 iters
            const float4 v = src[i];
            const int y = i / 20;                          // 20 float4s per row
            const int x = (i % 20) * 4;
            const int base = (y + 1) * PW + x + 1;
            s[base + 0] = v.x; s[base + 1] = v.y;
            s[base + 2] = v.z; s[base + 3] = v.w;
        }
        // zero border: row 0 (81 elems) and column 0 (rows 1..80)
        if (tid < 81)                s[tid] = 0.0f;
        if (tid >= 128 && tid < 208) s[(tid - 127) * PW] = 0.0f;
    }
    __syncthreads();

    // ---- Phase 2a: inclusive cumsum down each column ----
    if (tid < Wc) {
        const int cx = tid + 1;
        float run = 0.0f;
        #pragma unroll 8
        for (int y = 1; y <= Hc; ++y) {
            const int idx = y * PW + cx;
            run += s[idx];
            s[idx] = run;
        }
    }
    __syncthreads();

    // ---- Phase 2b: inclusive cumsum along each row ----
    if (tid < Hc) {
        const int ry = (tid + 1) * PW;
        float run = 0.0f;
        #pragma unroll 8
        for (int cx = 1; cx <= Wc; ++cx) {
            const int idx = ry + cx;
            run += s[idx];
            s[idx] = run;
        }
    }
    __syncthreads();

    // ---- Phase 3: one thread per box, 4 LDS lookups ----
    if (tid < Nc) {
        const float4 bx = ((const float4*)(boxes + (size_t)b * Nc * 4))[tid];

        // Mirror reference: (coord / 640) * 80, truncate, clip [0,80].
        int x1 = (int)(bx.x / 640.0f * 80.0f);
        int y1 = (int)(bx.y / 640.0f * 80.0f);
        int x2 = (int)(bx.z / 640.0f * 80.0f);
        int y2 = (int)(bx.w / 640.0f * 80.0f);
        x1 = min(max(x1, 0), Wc);  x2 = min(max(x2, 0), Wc);
        y1 = min(max(y1, 0), Hc);  y2 = min(max(y2, 0), Hc);

        const int dx = x2 - x1;
        const int dy = y2 - y1;

        float v = 0.0f;
        if (dx > 0 && dy > 0) {
            const float sum = s[y2 * PW + x2] - s[y1 * PW + x2]
                            - s[y2 * PW + x1] + s[y1 * PW + x1];
            v = sum / (float)(dy * dx);
        }
        out[((size_t)b * Nc + tid) * Cc + c] = v;
    }
}

extern "C" void kernel_launch(void* const* d_in, const int* in_sizes, int n_in,
                              void* d_out, int out_size, void* d_ws, size_t ws_size,
                              hipStream_t stream) {
    const float* fmap  = (const float*)d_in[0];
    const float* boxes = (const float*)d_in[1];
    float* out = (float*)d_out;

    dim3 grid(Bc * Cc);   // 16384 blocks, one per (b,c) plane
    dim3 block(256);
    roi_mean_pool_kernel<<<grid, block, 0, stream>>>(fmap, boxes, out);
}